// Round 7
// baseline (181.589 us; speedup 1.0000x reference)
//
#include <hip/hip_runtime.h>

// ---------------------------------------------------------------------------
// InfluenceGraphConv: out = segment_sum((feat@W * cu)[src] * edge_w, dst) * cv
// N=100000, E=1600000, D_IN=D_OUT=128, fp32 in/out (src/dst int32).
//
// 3-dispatch pipeline (+1 tiny memset):
//   0. memset ccur[512] = 0
//   1. fused:   blocks [0,FB)   = coarse_fill (LDS-binning into 256-node
//                                 buckets at implicit base b*cap)
//               blocks [FB,..)  = gemm_mfma  hb = bf16((feat@W)*cu)
//               (independent chains run concurrently in one dispatch)
//   2. finalize: per-bucket LDS count+scan -> rng[node]; scatter -> meta
//               (meta 4B: src(17b) | w_top15(15b)<<17, float = m & 0xFFFE0000)
//   3. gather:  one wave per node; lane-halves process edge pairs, uint2
//               row chunks (32 lanes = full 256B row); shfl_xor(32) combine
// All CSR-build atomics in LDS; no float atomics; output written once.
// ---------------------------------------------------------------------------

typedef __attribute__((ext_vector_type(8))) short short8;
typedef __attribute__((ext_vector_type(4))) float f32x4;

#define BSHIFT 8                    // 256 nodes per coarse bucket
#define CF_CHUNK 2048               // edges per fill block

static __device__ __forceinline__ ushort f2bf(float f) {
    uint b = __float_as_uint(f);
    uint r = b + 0x7fff + ((b >> 16) & 1);   // RNE
    return (ushort)(r >> 16);
}

// ---- 1. fused: coarse_fill (blocks < fill_blocks) + gemm_mfma -------------
__global__ __launch_bounds__(256) void fused_gemm_fill_kernel(
    const float* __restrict__ feat, const float* __restrict__ Wg,
    const float* __restrict__ cu, ushort* __restrict__ hb,
    const int* __restrict__ src, const int* __restrict__ dst,
    const float* __restrict__ edge_w, int* __restrict__ ccur,
    uint2* __restrict__ tmp, int cap, int n, int e, int fill_blocks)
{
    extern __shared__ char smem[];   // 32 KB union
    const int tid = threadIdx.x;

    if ((int)blockIdx.x < fill_blocks) {
        // ------------- fill role: LDS-staged bucket binning ----------------
        uint*   le0   = (uint*)smem;                 // [2048]  8 KB
        uint*   lw    = (uint*)(smem + 8192);        // [2048]  8 KB
        ushort* lb    = (ushort*)(smem + 16384);     // [2048]  4 KB
        int*    hist  = (int*)(smem + 20480);        // [512]   2 KB
        int*    hbase = (int*)(smem + 22528);        // [512]   2 KB
        int*    lcur  = (int*)(smem + 24576);        // [512]   2 KB
        const int base = blockIdx.x * CF_CHUNK;

        for (int t = tid; t < 512; t += 256) { hist[t] = 0; lcur[t] = 0; }
        __syncthreads();

        #pragma unroll
        for (int j = 0; j < CF_CHUNK / 256; ++j) {
            const int i  = base + j * 256 + tid;
            const int li = j * 256 + tid;
            if (i < e) {
                const int d = dst[i];
                const int b = d >> BSHIFT;
                le0[li] = (uint)src[i] | ((uint)(d & ((1 << BSHIFT) - 1)) << 17);
                lw[li]  = __float_as_uint(edge_w[i]);
                lb[li]  = (ushort)b;
                atomicAdd(&hist[b], 1);
            } else {
                lb[li] = 0xFFFF;
            }
        }
        __syncthreads();

        for (int t = tid; t < 512; t += 256)
            if (hist[t] > 0) hbase[t] = t * cap + atomicAdd(&ccur[t], hist[t]);
        __syncthreads();

        #pragma unroll
        for (int j = 0; j < CF_CHUNK / 256; ++j) {
            const int li = j * 256 + tid;
            const ushort b = lb[li];
            if (b != 0xFFFF) {
                const int pos = hbase[b] + atomicAdd(&lcur[b], 1);
                if (pos < (b + 1) * cap) {        // overflow guard
                    uint2 v; v.x = le0[li]; v.y = lw[li];
                    tmp[pos] = v;
                }
            }
        }
    } else {
        // ------------- gemm role: bf16 MFMA, W^T swizzled in LDS -----------
        char* const wp = smem;                       // 32 KB W^T bf16
        const int lane = tid & 63;
        const int wid  = tid >> 6;

        for (int i = tid; i < 128 * 128; i += 256) {
            const int k = i >> 7, d = i & 127;
            const int byte_addr = (d * 256 + k * 2) ^ ((d & 7) << 4);
            *(ushort*)(wp + byte_addr) = f2bf(Wg[i]);
        }
        __syncthreads();

        const int wave_row0 = (blockIdx.x - fill_blocks) * 256 + wid * 64;

        for (int rt = 0; rt < 4; ++rt) {
            const int r0 = wave_row0 + rt * 16;
            const int arow = min(r0 + (lane & 15), n - 1);
            const float* ap = feat + (size_t)arow * 128 + ((lane >> 4) * 8);

            short8 afr[4];
            #pragma unroll
            for (int kk = 0; kk < 4; ++kk) {
                const float4 f0 = *(const float4*)(ap + kk * 32);
                const float4 f1 = *(const float4*)(ap + kk * 32 + 4);
                short8 a;
                a[0] = (short)f2bf(f0.x); a[1] = (short)f2bf(f0.y);
                a[2] = (short)f2bf(f0.z); a[3] = (short)f2bf(f0.w);
                a[4] = (short)f2bf(f1.x); a[5] = (short)f2bf(f1.y);
                a[6] = (short)f2bf(f1.z); a[7] = (short)f2bf(f1.w);
                afr[kk] = a;
            }

            f32x4 acc[8];
            #pragma unroll
            for (int nf = 0; nf < 8; ++nf) acc[nf] = (f32x4)(0.f);

            #pragma unroll
            for (int kk = 0; kk < 4; ++kk) {
                const int kbyte = kk * 64 + ((lane >> 4) << 4);
                #pragma unroll
                for (int nf = 0; nf < 8; ++nf) {
                    const int col = nf * 16 + (lane & 15);
                    const short8 bfr = *(const short8*)(
                        wp + ((col * 256 + kbyte) ^ ((col & 7) << 4)));
                    acc[nf] = __builtin_amdgcn_mfma_f32_16x16x32_bf16(
                        afr[kk], bfr, acc[nf], 0, 0, 0);
                }
            }

            const int rbase = r0 + (lane >> 4) * 4;
            float cuv[4];
            #pragma unroll
            for (int i = 0; i < 4; ++i) cuv[i] = cu[min(rbase + i, n - 1)];
            #pragma unroll
            for (int nf = 0; nf < 8; ++nf) {
                const int col = nf * 16 + (lane & 15);
                #pragma unroll
                for (int i = 0; i < 4; ++i) {
                    const int row = rbase + i;
                    if (row < n)
                        hb[(size_t)row * 128 + col] = f2bf(acc[nf][i] * cuv[i]);
                }
            }
        }
    }
}

// ---- 2. per-bucket finalize: LDS count+scan -> rng; scatter -> meta -------
// meta entry (4B): src(17b) | w_top15(15b)<<17; float w = m & 0xFFFE0000
__global__ __launch_bounds__(256) void bucket_finalize_kernel(
    const uint2* __restrict__ tmp, const int* __restrict__ ccur, int cap,
    int2* __restrict__ rng, uint* __restrict__ meta, int n)
{
    __shared__ int lcnt[256];
    __shared__ int lcur[256];
    __shared__ int wsum[4];
    const int b = blockIdx.x;
    const int tid  = threadIdx.x;
    const int lane = tid & 63;
    const int wid  = tid >> 6;
    const int base = b * cap;
    const int cnt  = min(ccur[b], cap);
    const int ce   = base + cnt;
    const int node0 = b << BSHIFT;
    const int nn = min(1 << BSHIFT, n - node0);

    lcnt[tid] = 0;
    __syncthreads();

    for (int i = base + tid; i < ce; i += 256)
        atomicAdd(&lcnt[(tmp[i].x >> 17) & ((1 << BSHIFT) - 1)], 1);
    __syncthreads();

    // block exclusive scan of lcnt[0..256)
    const int v = lcnt[tid];
    int incl = v;
    #pragma unroll
    for (int off = 1; off < 64; off <<= 1) {
        int t = __shfl_up(incl, off);
        if (lane >= off) incl += t;
    }
    if (lane == 63) wsum[wid] = incl;
    __syncthreads();
    int wpre = 0;
    for (int k = 0; k < wid; ++k) wpre += wsum[k];
    const int excl = wpre + incl - v;
    lcur[tid] = excl;

    if (tid < nn) {
        int2 rr; rr.x = base + excl; rr.y = base + excl + v;
        rng[node0 + tid] = rr;
    }
    __syncthreads();

    // scatter into node-sorted meta (bucket region is L2-local)
    for (int i = base + tid; i < ce; i += 256) {
        const uint2 t2 = tmp[i];
        const int local = (t2.x >> 17) & ((1 << BSHIFT) - 1);
        const int pos = atomicAdd(&lcur[local], 1);
        const uint wb = t2.y;                       // fp32 bits, w >= 0
        const uint w17 = ((wb + 0xFFFFu + ((wb >> 17) & 1u)) >> 17) & 0x7FFFu;
        __builtin_nontemporal_store((t2.x & 0x1FFFFu) | (w17 << 17),
                                    &meta[base + pos]);
    }
}

// ---- 3. gather: one wave/node, lane-half edge pairs, uint2 row chunks -----
__global__ __launch_bounds__(256) void gather_kernel(
    const ushort* __restrict__ hb, const int2* __restrict__ rng,
    const uint* __restrict__ meta, const float* __restrict__ cv,
    float* __restrict__ out, int n)
{
    // bijective XCD-chunked swizzle (m204)
    const int nwg = gridDim.x;
    const int q = nwg >> 3, r = nwg & 7;
    const int xcd = blockIdx.x & 7, idx = blockIdx.x >> 3;
    const int bid = (xcd < r ? xcd * (q + 1) : r * (q + 1) + (xcd - r) * q) + idx;

    const int wave = threadIdx.x >> 6;
    const int lane = threadIdx.x & 63;
    const int half = lane >> 5;          // which edge of the pair
    const int c    = lane & 31;          // uint2 chunk within the 256B row
    const int node = bid * 4 + wave;
    if (node >= n) return;

    const int2 rg = rng[node];
    const int cnt = rg.y - rg.x;
    const uint* __restrict__ mp = meta + rg.x;
    const uint2* __restrict__ h64 = (const uint2*)hb;   // row = 32 uint2

    float a0 = 0.f, a1 = 0.f, a2 = 0.f, a3 = 0.f;
    const int npf = cnt >> 1;            // full pairs
    int p = 0;
    for (; p + 4 <= npf; p += 4) {       // 8 edges per iteration
        uint m[4];
        #pragma unroll
        for (int j = 0; j < 4; ++j)
            m[j] = __builtin_nontemporal_load(&mp[2 * (p + j) + half]);
        uint2 h[4];
        #pragma unroll
        for (int j = 0; j < 4; ++j)
            h[j] = h64[(size_t)(m[j] & 0x1FFFFu) * 32 + c];
        #pragma unroll
        for (int j = 0; j < 4; ++j) {
            const float w = __uint_as_float(m[j] & 0xFFFE0000u);
            a0 += __uint_as_float(h[j].x << 16) * w;
            a1 += __uint_as_float(h[j].x & 0xffff0000u) * w;
            a2 += __uint_as_float(h[j].y << 16) * w;
            a3 += __uint_as_float(h[j].y & 0xffff0000u) * w;
        }
    }
    for (; p < npf; ++p) {
        const uint m = __builtin_nontemporal_load(&mp[2 * p + half]);
        const uint2 h = h64[(size_t)(m & 0x1FFFFu) * 32 + c];
        const float w = __uint_as_float(m & 0xFFFE0000u);
        a0 += __uint_as_float(h.x << 16) * w;
        a1 += __uint_as_float(h.x & 0xffff0000u) * w;
        a2 += __uint_as_float(h.y << 16) * w;
        a3 += __uint_as_float(h.y & 0xffff0000u) * w;
    }
    if ((cnt & 1) && half == 0) {        // odd tail edge
        const uint m = mp[cnt - 1];
        const uint2 h = h64[(size_t)(m & 0x1FFFFu) * 32 + c];
        const float w = __uint_as_float(m & 0xFFFE0000u);
        a0 += __uint_as_float(h.x << 16) * w;
        a1 += __uint_as_float(h.x & 0xffff0000u) * w;
        a2 += __uint_as_float(h.y << 16) * w;
        a3 += __uint_as_float(h.y & 0xffff0000u) * w;
    }

    // combine the two halves
    a0 += __shfl_xor(a0, 32);
    a1 += __shfl_xor(a1, 32);
    a2 += __shfl_xor(a2, 32);
    a3 += __shfl_xor(a3, 32);

    if (half == 0) {
        const float cvv = cv[node];
        f32x4 o; o.x = a0 * cvv; o.y = a1 * cvv; o.z = a2 * cvv; o.w = a3 * cvv;
        __builtin_nontemporal_store(o, (f32x4*)out + (size_t)node * 32 + c);
    }
}

// -------- fallback (small ws / n too large for packing) --------------------
__global__ __launch_bounds__(256) void gemm_cu_kernel(
    const float* __restrict__ feat, const float* __restrict__ Wg,
    const float* __restrict__ cu, float* __restrict__ h_src, int n)
{
    __shared__ float wlds[128 * 128];
    __shared__ float ftile[128][32];
    const int tid = threadIdx.x;
    for (int i = tid; i < (128 * 128) / 4; i += 256)
        ((float4*)wlds)[i] = ((const float4*)Wg)[i];
    const int row0 = blockIdx.x * 32;
    {
        const int r  = tid & 31;
        const int kq = tid >> 5;
        const int grow = row0 + r;
        if (grow < n) {
            #pragma unroll
            for (int c = 0; c < 4; ++c) {
                float4 v = *(const float4*)(feat + (size_t)grow * 128 + kq * 16 + c * 4);
                ftile[kq * 16 + c * 4 + 0][r] = v.x;
                ftile[kq * 16 + c * 4 + 1][r] = v.y;
                ftile[kq * 16 + c * 4 + 2][r] = v.z;
                ftile[kq * 16 + c * 4 + 3][r] = v.w;
            }
        }
    }
    __syncthreads();
    const int d0 = (tid & 31) * 4;
    const int r0 = (tid >> 5) * 4;
    float acc[4][4] = {};
    #pragma unroll 8
    for (int k = 0; k < 128; ++k) {
        const float4 a = *(const float4*)&ftile[k][r0];
        const float4 b = *(const float4*)&wlds[k * 128 + d0];
        acc[0][0] += a.x * b.x; acc[0][1] += a.x * b.y; acc[0][2] += a.x * b.z; acc[0][3] += a.x * b.w;
        acc[1][0] += a.y * b.x; acc[1][1] += a.y * b.y; acc[1][2] += a.y * b.z; acc[1][3] += a.y * b.w;
        acc[2][0] += a.z * b.x; acc[2][1] += a.z * b.y; acc[2][2] += a.z * b.z; acc[2][3] += a.z * b.w;
        acc[3][0] += a.w * b.x; acc[3][1] += a.w * b.y; acc[3][2] += a.w * b.z; acc[3][3] += a.w * b.w;
    }
    #pragma unroll
    for (int i = 0; i < 4; ++i) {
        const int rr = row0 + r0 + i;
        if (rr < n) {
            const float c = cu[rr];
            float4 o;
            o.x = acc[i][0] * c; o.y = acc[i][1] * c;
            o.z = acc[i][2] * c; o.w = acc[i][3] * c;
            *(float4*)(h_src + (size_t)rr * 128 + d0) = o;
        }
    }
}

__global__ __launch_bounds__(256) void scatter_atomic_kernel(
    const float* __restrict__ h_src, const int* __restrict__ src,
    const int* __restrict__ dst, const float* __restrict__ edge_w,
    float* __restrict__ out, int e)
{
    long long t = (long long)blockIdx.x * 256 + threadIdx.x;
    int edge = (int)(t >> 5);
    int c4   = (int)(t & 31) * 4;
    if (edge >= e) return;
    int s = src[edge], d = dst[edge];
    float w = edge_w[edge];
    const float4 h = *(const float4*)(h_src + (size_t)s * 128 + c4);
    float* o = out + (size_t)d * 128 + c4;
    atomicAdd(o + 0, h.x * w);
    atomicAdd(o + 1, h.y * w);
    atomicAdd(o + 2, h.z * w);
    atomicAdd(o + 3, h.w * w);
}

__global__ __launch_bounds__(256) void cvscale_kernel(
    float* __restrict__ out, const float* __restrict__ cv, int n)
{
    size_t i = (size_t)blockIdx.x * 256 + threadIdx.x;
    if (i < (size_t)n * 128) out[i] *= cv[i >> 7];
}

// ---------------------------------------------------------------------------

static inline size_t align_up(size_t x, size_t a) { return (x + a - 1) & ~(a - 1); }

extern "C" void kernel_launch(void* const* d_in, const int* in_sizes, int n_in,
                              void* d_out, int out_size, void* d_ws, size_t ws_size,
                              hipStream_t stream)
{
    const float* feat   = (const float*)d_in[0];
    const float* W      = (const float*)d_in[1];
    const float* cu     = (const float*)d_in[2];
    const float* cv     = (const float*)d_in[3];
    const float* edge_w = (const float*)d_in[4];
    const int*   src    = (const int*)d_in[5];
    const int*   dst    = (const int*)d_in[6];
    float* out = (float*)d_out;

    const int n = in_sizes[2];   // N
    const int e = in_sizes[5];   // E
    const int nb = (n + (1 << BSHIFT) - 1) >> BSHIFT;   // coarse buckets

    // over-allocated bucket capacity (uniform dst => cap never hit)
    const int avg = (e + nb - 1) / nb;
    const int cap = (avg + avg / 2 + 1024 + 31) & ~31;
    const size_t slots = (size_t)nb * cap;

    // workspace layout
    char* ws = (char*)d_ws;
    size_t off = 0;
    ushort* hb  = (ushort*)(ws + off); off += align_up((size_t)n * 128 * sizeof(ushort), 256);
    int2*  rng  = (int2*)(ws + off);   off += align_up((size_t)n * sizeof(int2), 256);
    int*   ccur = (int*)(ws + off);    off += align_up(512 * sizeof(int), 256);
    uint*  meta = (uint*)(ws + off);   off += align_up(slots * sizeof(uint), 256);
    uint2* tmp  = (uint2*)(ws + off);  off += align_up(slots * sizeof(uint2), 256);
    const size_t need_primary = off;
    const size_t need_fallback = align_up((size_t)n * 128 * sizeof(float), 256);

    const bool pack_ok = (n <= (1 << 17)) && (nb <= 512);

    if (pack_ok && ws_size >= need_primary) {
        const int FB = (e + CF_CHUNK - 1) / CF_CHUNK;   // fill blocks
        const int GB = (n + 255) / 256;                 // gemm blocks
        hipMemsetAsync(ccur, 0, 512 * sizeof(int), stream);
        fused_gemm_fill_kernel<<<FB + GB, 256, 32768, stream>>>(
            feat, W, cu, hb, src, dst, edge_w, ccur, tmp, cap, n, e, FB);
        bucket_finalize_kernel<<<nb, 256, 0, stream>>>(tmp, ccur, cap, rng, meta, n);
        gather_kernel<<<(n + 3) / 4, 256, 0, stream>>>(hb, rng, meta, cv, out, n);
    } else if (ws_size >= need_fallback) {
        float* h_src = (float*)ws;
        hipMemsetAsync(out, 0, (size_t)n * 128 * sizeof(float), stream);
        gemm_cu_kernel<<<(n + 31) / 32, 256, 0, stream>>>(feat, W, cu, h_src, n);
        const long long thr = (long long)e * 32;
        scatter_atomic_kernel<<<(int)((thr + 255) / 256), 256, 0, stream>>>(h_src, src, dst, edge_w, out, e);
        cvscale_kernel<<<(int)(((size_t)n * 128 + 255) / 256), 256, 0, stream>>>(out, cv, n);
    }
}

// Round 8
// 171.080 us; speedup vs baseline: 1.0614x; 1.0614x over previous
//
#include <hip/hip_runtime.h>

// ---------------------------------------------------------------------------
// InfluenceGraphConv: out = segment_sum((feat@W * cu)[src] * edge_w, dst) * cv
// N=100000, E=1600000, D_IN=D_OUT=128, fp32 in/out (src/dst int32).
//
// 4-dispatch pipeline (round-6 structure + src-sorted edge lists):
//   1. gemm_mfma:       hb[n][d] = bf16((feat[n].W[:,d]) * cu[n]); block 0
//                       also zeroes the 256 coarse-bucket cursors
//   2. coarse_fill:     LDS-staged binning into 512-node buckets at
//                       implicit base b*cap (over-allocated, no scan needed)
//   3. bucket_finalize: per-bucket LDS count+scan -> rng[node]; scatter into
//                       LDS; per-node INSERTION SORT BY SRC (gives all
//                       concurrent gather waves a lock-step sweep of the
//                       h-table -> L2-resident working set); coalesced
//                       writeback -> meta (4B: src(17b) | w_bf15<<17)
//   4. gather:          one wave per node, bf16 rows, 8-deep unroll
// All CSR-build atomics in LDS; no float atomics; output written once.
// ---------------------------------------------------------------------------

typedef __attribute__((ext_vector_type(8))) short short8;
typedef __attribute__((ext_vector_type(4))) float f32x4;

#define BSHIFT 9                    // 512 nodes per coarse bucket
#define CF_CHUNK 4096               // edges per coarse_fill block
#define SMETA_CAP 14336             // LDS sort buffer entries (57.3 KB)

static __device__ __forceinline__ ushort f2bf(float f) {
    uint b = __float_as_uint(f);
    uint r = b + 0x7fff + ((b >> 16) & 1);   // RNE
    return (ushort)(r >> 16);
}

// ---- 1. bf16 MFMA GEMM + cu scale, bf16 output ----------------------------
__global__ __launch_bounds__(256) void gemm_mfma_kernel(
    const float* __restrict__ feat, const float* __restrict__ Wg,
    const float* __restrict__ cu, ushort* __restrict__ hb,
    int* __restrict__ ccur, int n)
{
    __shared__ ushort wt[128 * 128];      // 32 KB, W^T bf16, swizzled
    char* const wp = (char*)wt;
    const int tid  = threadIdx.x;
    const int lane = tid & 63;
    const int wid  = tid >> 6;

    // zero bucket cursors (stream-ordered before coarse_fill)
    if (blockIdx.x == 0) ccur[tid] = 0;

    for (int i = tid; i < 128 * 128; i += 256) {
        const int k = i >> 7, d = i & 127;
        const int byte_addr = (d * 256 + k * 2) ^ ((d & 7) << 4);
        *(ushort*)(wp + byte_addr) = f2bf(Wg[i]);
    }
    __syncthreads();

    const int wave_row0 = blockIdx.x * 256 + wid * 64;

    for (int rt = 0; rt < 4; ++rt) {
        const int r0 = wave_row0 + rt * 16;
        const int arow = min(r0 + (lane & 15), n - 1);
        const float* ap = feat + (size_t)arow * 128 + ((lane >> 4) * 8);

        short8 afr[4];
        #pragma unroll
        for (int kk = 0; kk < 4; ++kk) {
            const float4 f0 = *(const float4*)(ap + kk * 32);
            const float4 f1 = *(const float4*)(ap + kk * 32 + 4);
            short8 a;
            a[0] = (short)f2bf(f0.x); a[1] = (short)f2bf(f0.y);
            a[2] = (short)f2bf(f0.z); a[3] = (short)f2bf(f0.w);
            a[4] = (short)f2bf(f1.x); a[5] = (short)f2bf(f1.y);
            a[6] = (short)f2bf(f1.z); a[7] = (short)f2bf(f1.w);
            afr[kk] = a;
        }

        f32x4 acc[8];
        #pragma unroll
        for (int nf = 0; nf < 8; ++nf) acc[nf] = (f32x4)(0.f);

        #pragma unroll
        for (int kk = 0; kk < 4; ++kk) {
            const int kbyte = kk * 64 + ((lane >> 4) << 4);
            #pragma unroll
            for (int nf = 0; nf < 8; ++nf) {
                const int col = nf * 16 + (lane & 15);
                const short8 bfr = *(const short8*)(
                    wp + ((col * 256 + kbyte) ^ ((col & 7) << 4)));
                acc[nf] = __builtin_amdgcn_mfma_f32_16x16x32_bf16(
                    afr[kk], bfr, acc[nf], 0, 0, 0);
            }
        }

        const int rbase = r0 + (lane >> 4) * 4;
        float cuv[4];
        #pragma unroll
        for (int i = 0; i < 4; ++i) cuv[i] = cu[min(rbase + i, n - 1)];
        #pragma unroll
        for (int nf = 0; nf < 8; ++nf) {
            const int col = nf * 16 + (lane & 15);
            #pragma unroll
            for (int i = 0; i < 4; ++i) {
                const int row = rbase + i;
                if (row < n)
                    hb[(size_t)row * 128 + col] = f2bf(acc[nf][i] * cuv[i]);
            }
        }
    }
}

// ---- 2. coarse fill: LDS-staged binning into 512-node buckets -------------
// tmp entry: x = src | (dstoff<<17)  (requires n <= 131072), y = bits(edge_w)
// bucket b's region = tmp[b*cap .. b*cap+ccur[b])
__global__ __launch_bounds__(256) void coarse_fill_kernel(
    const int* __restrict__ src, const int* __restrict__ dst,
    const float* __restrict__ edge_w, int* __restrict__ ccur,
    uint2* __restrict__ tmp, int cap, int e)
{
    __shared__ uint   le0[CF_CHUNK];     // 16 KB
    __shared__ uint   lw[CF_CHUNK];      // 16 KB
    __shared__ ushort lb[CF_CHUNK];      //  8 KB (bucket id; 0xFFFF = invalid)
    __shared__ int    hist[256];
    __shared__ int    hbase[256];
    __shared__ int    lcur[256];
    const int tid  = threadIdx.x;
    const int base = blockIdx.x * CF_CHUNK;

    hist[tid] = 0; lcur[tid] = 0;
    __syncthreads();

    #pragma unroll
    for (int j = 0; j < CF_CHUNK / 256; ++j) {
        const int i  = base + j * 256 + tid;
        const int li = j * 256 + tid;
        if (i < e) {
            const int d = dst[i];
            const int b = d >> BSHIFT;
            le0[li] = (uint)src[i] | ((uint)(d & ((1 << BSHIFT) - 1)) << 17);
            lw[li]  = __float_as_uint(edge_w[i]);
            lb[li]  = (ushort)b;
            atomicAdd(&hist[b], 1);
        } else {
            lb[li] = 0xFFFF;
        }
    }
    __syncthreads();

    if (hist[tid] > 0)
        hbase[tid] = tid * cap + atomicAdd(&ccur[tid], hist[tid]);
    __syncthreads();

    #pragma unroll
    for (int j = 0; j < CF_CHUNK / 256; ++j) {
        const int li = j * 256 + tid;
        const ushort b = lb[li];
        if (b != 0xFFFF) {
            const int pos = hbase[b] + atomicAdd(&lcur[b], 1);
            if (pos < (b + 1) * cap) {            // overflow guard
                uint2 v; v.x = le0[li]; v.y = lw[li];
                tmp[pos] = v;
            }
        }
    }
}

// ---- 3. per-bucket finalize: count+scan -> rng; LDS scatter + per-node ----
//      src-sort; coalesced writeback -> meta (4B: src | w_bf15<<17)
__global__ __launch_bounds__(512) void bucket_finalize_kernel(
    const uint2* __restrict__ tmp, const int* __restrict__ ccur, int cap,
    int2* __restrict__ rng, uint* __restrict__ meta, int n)
{
    __shared__ uint smeta[SMETA_CAP];    // 57.3 KB sort buffer
    __shared__ int lcnt[512];
    __shared__ int lexcl[512];
    __shared__ int lcur[512];
    __shared__ int wsum[8];
    const int b = blockIdx.x;
    const int tid  = threadIdx.x;
    const int lane = tid & 63;
    const int wid  = tid >> 6;
    const int base = b * cap;
    const int cnt  = min(ccur[b], cap);
    const int ce   = base + cnt;
    const int node0 = b << BSHIFT;
    const int nn = min(1 << BSHIFT, n - node0);

    lcnt[tid] = 0;
    __syncthreads();

    for (int i = base + tid; i < ce; i += 512)
        atomicAdd(&lcnt[(tmp[i].x >> 17) & ((1 << BSHIFT) - 1)], 1);
    __syncthreads();

    // block exclusive scan of lcnt[0..512)
    const int v = lcnt[tid];
    int incl = v;
    #pragma unroll
    for (int off = 1; off < 64; off <<= 1) {
        int t = __shfl_up(incl, off);
        if (lane >= off) incl += t;
    }
    if (lane == 63) wsum[wid] = incl;
    __syncthreads();
    int wpre = 0;
    for (int k = 0; k < wid; ++k) wpre += wsum[k];
    const int excl = wpre + incl - v;
    lexcl[tid] = excl;
    lcur[tid]  = excl;

    if (tid < nn) {
        int2 rr; rr.x = base + excl; rr.y = base + excl + v;
        rng[node0 + tid] = rr;
    }
    __syncthreads();

    if (cnt <= SMETA_CAP) {
        // scatter into LDS (node-sorted)
        for (int i = base + tid; i < ce; i += 512) {
            const uint2 t2 = tmp[i];
            const int local = (t2.x >> 17) & ((1 << BSHIFT) - 1);
            const int pos = atomicAdd(&lcur[local], 1);
            const uint wb = t2.y;                   // fp32 bits, w >= 0
            const uint w15 = ((wb + 0x7fffu + ((wb >> 16) & 1u)) >> 16) & 0x7FFFu;
            smeta[pos] = (t2.x & 0x1FFFFu) | (w15 << 17);
        }
        __syncthreads();
        // per-node insertion sort by src (perf-only: gives concurrent gather
        // waves a lock-step sweep of the h-table -> L2-resident working set)
        for (int t = tid; t < nn; t += 512) {
            const int s0 = lexcl[t];
            const int s1 = s0 + lcnt[t];
            for (int i = s0 + 1; i < s1; ++i) {
                const uint key = smeta[i];
                const uint ks = key & 0x1FFFFu;
                int j = i - 1;
                while (j >= s0 && (smeta[j] & 0x1FFFFu) > ks) {
                    smeta[j + 1] = smeta[j];
                    --j;
                }
                smeta[j + 1] = key;
            }
        }
        __syncthreads();
        // coalesced writeback
        for (int i = tid; i < cnt; i += 512)
            meta[base + i] = smeta[i];
    } else {
        // fallback: direct global scatter, unsorted (still correct)
        for (int i = base + tid; i < ce; i += 512) {
            const uint2 t2 = tmp[i];
            const int local = (t2.x >> 17) & ((1 << BSHIFT) - 1);
            const int pos = atomicAdd(&lcur[local], 1);
            const uint wb = t2.y;
            const uint w15 = ((wb + 0x7fffu + ((wb >> 16) & 1u)) >> 16) & 0x7FFFu;
            meta[base + pos] = (t2.x & 0x1FFFFu) | (w15 << 17);
        }
    }
}

// ---- 4. gather: one wave per node, bf16 rows, 8-deep unroll ---------------
__global__ __launch_bounds__(256) void gather_kernel(
    const ushort* __restrict__ hb, const int2* __restrict__ rng,
    const uint* __restrict__ meta, const float* __restrict__ cv,
    float* __restrict__ out, int n)
{
    // bijective XCD-chunked swizzle (m204): contiguous node ranges per XCD
    const int nwg = gridDim.x;
    const int q = nwg >> 3, r = nwg & 7;
    const int xcd = blockIdx.x & 7, idx = blockIdx.x >> 3;
    const int bid = (xcd < r ? xcd * (q + 1) : r * (q + 1) + (xcd - r) * q) + idx;

    const int wave = threadIdx.x >> 6;
    const int lane = threadIdx.x & 63;
    const int node = bid * 4 + wave;
    if (node >= n) return;

    const int2 rg = rng[node];
    const int beg = rg.x;
    const int end = rg.y;
    const uint* __restrict__ h32 = (const uint*)hb;   // bf16x2 words

    float ax = 0.f, ay = 0.f;
    int p = beg;
    for (; p + 8 <= end; p += 8) {
        uint m[8];
        #pragma unroll
        for (int j = 0; j < 8; ++j) m[j] = meta[p + j];
        uint h[8];
        #pragma unroll
        for (int j = 0; j < 8; ++j)
            h[j] = h32[(size_t)(m[j] & 0x1FFFFu) * 64 + lane];
        #pragma unroll
        for (int j = 0; j < 8; ++j) {
            const float w = __uint_as_float((m[j] >> 17) << 16);
            ax += __uint_as_float(h[j] << 16) * w;
            ay += __uint_as_float(h[j] & 0xffff0000u) * w;
        }
    }
    for (; p + 4 <= end; p += 4) {
        uint m[4];
        #pragma unroll
        for (int j = 0; j < 4; ++j) m[j] = meta[p + j];
        uint h[4];
        #pragma unroll
        for (int j = 0; j < 4; ++j)
            h[j] = h32[(size_t)(m[j] & 0x1FFFFu) * 64 + lane];
        #pragma unroll
        for (int j = 0; j < 4; ++j) {
            const float w = __uint_as_float((m[j] >> 17) << 16);
            ax += __uint_as_float(h[j] << 16) * w;
            ay += __uint_as_float(h[j] & 0xffff0000u) * w;
        }
    }
    for (; p < end; ++p) {
        const uint m = meta[p];
        const uint h = h32[(size_t)(m & 0x1FFFFu) * 64 + lane];
        const float w = __uint_as_float((m >> 17) << 16);
        ax += __uint_as_float(h << 16) * w;
        ay += __uint_as_float(h & 0xffff0000u) * w;
    }

    const float c = cv[node];
    float2 o; o.x = ax * c; o.y = ay * c;
    ((float2*)out)[(size_t)node * 64 + lane] = o;
}

// -------- fallback (small ws / n too large for packing) --------------------
__global__ __launch_bounds__(256) void gemm_cu_kernel(
    const float* __restrict__ feat, const float* __restrict__ Wg,
    const float* __restrict__ cu, float* __restrict__ h_src, int n)
{
    __shared__ float wlds[128 * 128];
    __shared__ float ftile[128][32];
    const int tid = threadIdx.x;
    for (int i = tid; i < (128 * 128) / 4; i += 256)
        ((float4*)wlds)[i] = ((const float4*)Wg)[i];
    const int row0 = blockIdx.x * 32;
    {
        const int r  = tid & 31;
        const int kq = tid >> 5;
        const int grow = row0 + r;
        if (grow < n) {
            #pragma unroll
            for (int c = 0; c < 4; ++c) {
                float4 v = *(const float4*)(feat + (size_t)grow * 128 + kq * 16 + c * 4);
                ftile[kq * 16 + c * 4 + 0][r] = v.x;
                ftile[kq * 16 + c * 4 + 1][r] = v.y;
                ftile[kq * 16 + c * 4 + 2][r] = v.z;
                ftile[kq * 16 + c * 4 + 3][r] = v.w;
            }
        }
    }
    __syncthreads();
    const int d0 = (tid & 31) * 4;
    const int r0 = (tid >> 5) * 4;
    float acc[4][4] = {};
    #pragma unroll 8
    for (int k = 0; k < 128; ++k) {
        const float4 a = *(const float4*)&ftile[k][r0];
        const float4 b = *(const float4*)&wlds[k * 128 + d0];
        acc[0][0] += a.x * b.x; acc[0][1] += a.x * b.y; acc[0][2] += a.x * b.z; acc[0][3] += a.x * b.w;
        acc[1][0] += a.y * b.x; acc[1][1] += a.y * b.y; acc[1][2] += a.y * b.z; acc[1][3] += a.y * b.w;
        acc[2][0] += a.z * b.x; acc[2][1] += a.z * b.y; acc[2][2] += a.z * b.z; acc[2][3] += a.z * b.w;
        acc[3][0] += a.w * b.x; acc[3][1] += a.w * b.y; acc[3][2] += a.w * b.z; acc[3][3] += a.w * b.w;
    }
    #pragma unroll
    for (int i = 0; i < 4; ++i) {
        const int rr = row0 + r0 + i;
        if (rr < n) {
            const float c = cu[rr];
            float4 o;
            o.x = acc[i][0] * c; o.y = acc[i][1] * c;
            o.z = acc[i][2] * c; o.w = acc[i][3] * c;
            *(float4*)(h_src + (size_t)rr * 128 + d0) = o;
        }
    }
}

__global__ __launch_bounds__(256) void scatter_atomic_kernel(
    const float* __restrict__ h_src, const int* __restrict__ src,
    const int* __restrict__ dst, const float* __restrict__ edge_w,
    float* __restrict__ out, int e)
{
    long long t = (long long)blockIdx.x * 256 + threadIdx.x;
    int edge = (int)(t >> 5);
    int c4   = (int)(t & 31) * 4;
    if (edge >= e) return;
    int s = src[edge], d = dst[edge];
    float w = edge_w[edge];
    const float4 h = *(const float4*)(h_src + (size_t)s * 128 + c4);
    float* o = out + (size_t)d * 128 + c4;
    atomicAdd(o + 0, h.x * w);
    atomicAdd(o + 1, h.y * w);
    atomicAdd(o + 2, h.z * w);
    atomicAdd(o + 3, h.w * w);
}

__global__ __launch_bounds__(256) void cvscale_kernel(
    float* __restrict__ out, const float* __restrict__ cv, int n)
{
    size_t i = (size_t)blockIdx.x * 256 + threadIdx.x;
    if (i < (size_t)n * 128) out[i] *= cv[i >> 7];
}

// ---------------------------------------------------------------------------

static inline size_t align_up(size_t x, size_t a) { return (x + a - 1) & ~(a - 1); }

extern "C" void kernel_launch(void* const* d_in, const int* in_sizes, int n_in,
                              void* d_out, int out_size, void* d_ws, size_t ws_size,
                              hipStream_t stream)
{
    const float* feat   = (const float*)d_in[0];
    const float* W      = (const float*)d_in[1];
    const float* cu     = (const float*)d_in[2];
    const float* cv     = (const float*)d_in[3];
    const float* edge_w = (const float*)d_in[4];
    const int*   src    = (const int*)d_in[5];
    const int*   dst    = (const int*)d_in[6];
    float* out = (float*)d_out;

    const int n = in_sizes[2];   // N
    const int e = in_sizes[5];   // E
    const int nb = (n + (1 << BSHIFT) - 1) >> BSHIFT; // coarse buckets (<=256)

    // over-allocated bucket capacity (uniform dst => cap never hit)
    const int avg = (e + nb - 1) / nb;
    const int cap = (avg + avg / 2 + 2048 + 31) & ~31;
    const size_t slots = (size_t)nb * cap;

    // workspace layout
    char* ws = (char*)d_ws;
    size_t off = 0;
    ushort* hb  = (ushort*)(ws + off); off += align_up((size_t)n * 128 * sizeof(ushort), 256);
    int2*  rng  = (int2*)(ws + off);   off += align_up((size_t)n * sizeof(int2), 256);
    int*   ccur = (int*)(ws + off);    off += align_up(256 * sizeof(int), 256);
    uint*  meta = (uint*)(ws + off);   off += align_up(slots * sizeof(uint), 256);
    uint2* tmp  = (uint2*)(ws + off);  off += align_up(slots * sizeof(uint2), 256);
    const size_t need_primary = off;
    const size_t need_fallback = align_up((size_t)n * 128 * sizeof(float), 256);

    const bool pack_ok = (n <= (1 << 17)) && (nb <= 256);

    if (pack_ok && ws_size >= need_primary) {
        gemm_mfma_kernel<<<(n + 255) / 256, 256, 0, stream>>>(feat, W, cu, hb, ccur, n);
        coarse_fill_kernel<<<(e + CF_CHUNK - 1) / CF_CHUNK, 256, 0, stream>>>(
            src, dst, edge_w, ccur, tmp, cap, e);
        bucket_finalize_kernel<<<nb, 512, 0, stream>>>(tmp, ccur, cap, rng, meta, n);
        gather_kernel<<<(n + 3) / 4, 256, 0, stream>>>(hb, rng, meta, cv, out, n);
    } else if (ws_size >= need_fallback) {
        float* h_src = (float*)ws;
        hipMemsetAsync(out, 0, (size_t)n * 128 * sizeof(float), stream);
        gemm_cu_kernel<<<(n + 31) / 32, 256, 0, stream>>>(feat, W, cu, h_src, n);
        const long long thr = (long long)e * 32;
        scatter_atomic_kernel<<<(int)((thr + 255) / 256), 256, 0, stream>>>(h_src, src, dst, edge_w, out, e);
        cvscale_kernel<<<(int)(((size_t)n * 128 + 255) / 256), 256, 0, stream>>>(out, cv, n);
    }
}

// Round 9
// 136.671 us; speedup vs baseline: 1.3287x; 1.2518x over previous
//
#include <hip/hip_runtime.h>

// ---------------------------------------------------------------------------
// InfluenceGraphConv: out = segment_sum((feat@W * cu)[src] * edge_w, dst) * cv
// N=100000, E=1600000, D_IN=D_OUT=128, fp32 in/out (src/dst int32).
//
// 5-dispatch pipeline (round-6 structure + staging/occupancy trims):
//   0. wconv:           W -> bf16 W^T, PRE-SWIZZLED bytes (LDS-image);
//                       also zeroes the 256 coarse-bucket cursors
//   1. gemm_mfma:       hb[n][d] = bf16((feat[n].W[:,d]) * cu[n]);
//                       W staged into LDS as 8 uint4 copies/thread
//   2. coarse_fill:     LDS-staged binning into 512-node buckets at
//                       implicit base b*cap (over-allocated, no scan)
//   3. bucket_finalize: per-bucket LDS count+scan -> rng[node]; scatter
//                       -> meta (4B: src(17b)|w_bf15<<17); 1024 thr/block
//   4. gather:          one wave per node, bf16 rows, 16-deep unroll
// All CSR-build atomics in LDS; no float atomics; output written once.
// ---------------------------------------------------------------------------

typedef __attribute__((ext_vector_type(8))) short short8;
typedef __attribute__((ext_vector_type(4))) float f32x4;

#define BSHIFT 9                    // 512 nodes per coarse bucket
#define CF_CHUNK 4096               // edges per coarse_fill block

static __device__ __forceinline__ ushort f2bf(float f) {
    uint b = __float_as_uint(f);
    uint r = b + 0x7fff + ((b >> 16) & 1);   // RNE
    return (ushort)(r >> 16);
}

// ---- 0. W pre-convert: bf16 W^T with the gemm LDS swizzle baked in --------
__global__ __launch_bounds__(256) void wconv_kernel(
    const float* __restrict__ Wg, ushort* __restrict__ wbf,
    int* __restrict__ ccur)
{
    const int tid = threadIdx.x;
    if (blockIdx.x == 0) ccur[tid] = 0;      // stream-ordered before fill
    char* const wp = (char*)wbf;
    for (int i = blockIdx.x * 256 + tid; i < 128 * 128; i += gridDim.x * 256) {
        const int k = i >> 7, d = i & 127;   // W[k][d]
        const int byte_addr = (d * 256 + k * 2) ^ ((d & 7) << 4);
        *(ushort*)(wp + byte_addr) = f2bf(Wg[i]);
    }
}

// ---- 1. bf16 MFMA GEMM + cu scale, bf16 output ----------------------------
__global__ __launch_bounds__(256) void gemm_mfma_kernel(
    const float* __restrict__ feat, const ushort* __restrict__ wbf,
    const float* __restrict__ cu, ushort* __restrict__ hb, int n)
{
    __shared__ ushort wt[128 * 128];      // 32 KB, byte-image of wbf
    char* const wp = (char*)wt;
    const int tid  = threadIdx.x;
    const int lane = tid & 63;
    const int wid  = tid >> 6;

    // stage pre-swizzled W: 2048 uint4 = 8 per thread
    {
        const uint4* wv = (const uint4*)wbf;
        #pragma unroll
        for (int j = 0; j < 8; ++j)
            ((uint4*)wt)[tid + j * 256] = wv[tid + j * 256];
    }
    __syncthreads();

    const int wave_row0 = blockIdx.x * 256 + wid * 64;

    for (int rt = 0; rt < 4; ++rt) {
        const int r0 = wave_row0 + rt * 16;
        const int arow = min(r0 + (lane & 15), n - 1);
        const float* ap = feat + (size_t)arow * 128 + ((lane >> 4) * 8);

        short8 afr[4];
        #pragma unroll
        for (int kk = 0; kk < 4; ++kk) {
            const float4 f0 = *(const float4*)(ap + kk * 32);
            const float4 f1 = *(const float4*)(ap + kk * 32 + 4);
            short8 a;
            a[0] = (short)f2bf(f0.x); a[1] = (short)f2bf(f0.y);
            a[2] = (short)f2bf(f0.z); a[3] = (short)f2bf(f0.w);
            a[4] = (short)f2bf(f1.x); a[5] = (short)f2bf(f1.y);
            a[6] = (short)f2bf(f1.z); a[7] = (short)f2bf(f1.w);
            afr[kk] = a;
        }

        f32x4 acc[8];
        #pragma unroll
        for (int nf = 0; nf < 8; ++nf) acc[nf] = (f32x4)(0.f);

        #pragma unroll
        for (int kk = 0; kk < 4; ++kk) {
            const int kbyte = kk * 64 + ((lane >> 4) << 4);
            #pragma unroll
            for (int nf = 0; nf < 8; ++nf) {
                const int col = nf * 16 + (lane & 15);
                const short8 bfr = *(const short8*)(
                    wp + ((col * 256 + kbyte) ^ ((col & 7) << 4)));
                acc[nf] = __builtin_amdgcn_mfma_f32_16x16x32_bf16(
                    afr[kk], bfr, acc[nf], 0, 0, 0);
            }
        }

        const int rbase = r0 + (lane >> 4) * 4;
        float cuv[4];
        #pragma unroll
        for (int i = 0; i < 4; ++i) cuv[i] = cu[min(rbase + i, n - 1)];
        #pragma unroll
        for (int nf = 0; nf < 8; ++nf) {
            const int col = nf * 16 + (lane & 15);
            #pragma unroll
            for (int i = 0; i < 4; ++i) {
                const int row = rbase + i;
                if (row < n)
                    hb[(size_t)row * 128 + col] = f2bf(acc[nf][i] * cuv[i]);
            }
        }
    }
}

// ---- 2. coarse fill: LDS-staged binning into 512-node buckets -------------
// tmp entry: x = src | (dstoff<<17)  (requires n <= 131072), y = bits(edge_w)
// bucket b's region = tmp[b*cap .. b*cap+ccur[b])
__global__ __launch_bounds__(256) void coarse_fill_kernel(
    const int* __restrict__ src, const int* __restrict__ dst,
    const float* __restrict__ edge_w, int* __restrict__ ccur,
    uint2* __restrict__ tmp, int cap, int e)
{
    __shared__ uint   le0[CF_CHUNK];     // 16 KB
    __shared__ uint   lw[CF_CHUNK];      // 16 KB
    __shared__ ushort lb[CF_CHUNK];      //  8 KB (bucket id; 0xFFFF = invalid)
    __shared__ int    hist[256];
    __shared__ int    hbase[256];
    __shared__ int    lcur[256];
    const int tid  = threadIdx.x;
    const int base = blockIdx.x * CF_CHUNK;

    hist[tid] = 0; lcur[tid] = 0;
    __syncthreads();

    #pragma unroll
    for (int j = 0; j < CF_CHUNK / 256; ++j) {
        const int i  = base + j * 256 + tid;
        const int li = j * 256 + tid;
        if (i < e) {
            const int d = dst[i];
            const int b = d >> BSHIFT;
            le0[li] = (uint)src[i] | ((uint)(d & ((1 << BSHIFT) - 1)) << 17);
            lw[li]  = __float_as_uint(edge_w[i]);
            lb[li]  = (ushort)b;
            atomicAdd(&hist[b], 1);
        } else {
            lb[li] = 0xFFFF;
        }
    }
    __syncthreads();

    if (hist[tid] > 0)
        hbase[tid] = tid * cap + atomicAdd(&ccur[tid], hist[tid]);
    __syncthreads();

    #pragma unroll
    for (int j = 0; j < CF_CHUNK / 256; ++j) {
        const int li = j * 256 + tid;
        const ushort b = lb[li];
        if (b != 0xFFFF) {
            const int pos = hbase[b] + atomicAdd(&lcur[b], 1);
            if (pos < (b + 1) * cap) {            // overflow guard
                uint2 v; v.x = le0[li]; v.y = lw[li];
                tmp[pos] = v;
            }
        }
    }
}

// ---- 3. per-bucket finalize: LDS count+scan -> rng; scatter -> meta -------
// meta entry (4B): src(17b) | w_bf15(15b)<<17
__global__ __launch_bounds__(1024) void bucket_finalize_kernel(
    const uint2* __restrict__ tmp, const int* __restrict__ ccur, int cap,
    int2* __restrict__ rng, uint* __restrict__ meta, int n)
{
    __shared__ int lcnt[512];
    __shared__ int lcur[512];
    __shared__ int wsum[16];
    const int b = blockIdx.x;
    const int tid  = threadIdx.x;
    const int lane = tid & 63;
    const int wid  = tid >> 6;
    const int base = b * cap;
    const int cnt  = min(ccur[b], cap);
    const int ce   = base + cnt;
    const int node0 = b << BSHIFT;
    const int nn = min(1 << BSHIFT, n - node0);

    if (tid < 512) lcnt[tid] = 0;
    __syncthreads();

    for (int i = base + tid; i < ce; i += 1024)
        atomicAdd(&lcnt[(tmp[i].x >> 17) & ((1 << BSHIFT) - 1)], 1);
    __syncthreads();

    // block exclusive scan of lcnt[0..512) (threads >=512 contribute 0)
    const int v = (tid < 512) ? lcnt[tid] : 0;
    int incl = v;
    #pragma unroll
    for (int off = 1; off < 64; off <<= 1) {
        int t = __shfl_up(incl, off);
        if (lane >= off) incl += t;
    }
    if (lane == 63) wsum[wid] = incl;
    __syncthreads();
    int wpre = 0;
    for (int k = 0; k < wid; ++k) wpre += wsum[k];
    const int excl = wpre + incl - v;
    if (tid < 512) lcur[tid] = excl;

    if (tid < nn) {
        int2 rr; rr.x = base + excl; rr.y = base + excl + v;
        rng[node0 + tid] = rr;
    }
    __syncthreads();

    // scatter into node-sorted meta (bucket region is L2-local)
    for (int i = base + tid; i < ce; i += 1024) {
        const uint2 t2 = tmp[i];
        const int local = (t2.x >> 17) & ((1 << BSHIFT) - 1);
        const int pos = atomicAdd(&lcur[local], 1);
        const uint wb = t2.y;                       // fp32 bits, w >= 0
        const uint w15 = ((wb + 0x7fffu + ((wb >> 16) & 1u)) >> 16) & 0x7FFFu;
        meta[base + pos] = (t2.x & 0x1FFFFu) | (w15 << 17);
    }
}

// ---- 4. gather: one wave per node, bf16 rows, 16-deep unroll --------------
__global__ __launch_bounds__(256) void gather_kernel(
    const ushort* __restrict__ hb, const int2* __restrict__ rng,
    const uint* __restrict__ meta, const float* __restrict__ cv,
    float* __restrict__ out, int n)
{
    // bijective XCD-chunked swizzle (m204): contiguous node ranges per XCD
    const int nwg = gridDim.x;
    const int q = nwg >> 3, r = nwg & 7;
    const int xcd = blockIdx.x & 7, idx = blockIdx.x >> 3;
    const int bid = (xcd < r ? xcd * (q + 1) : r * (q + 1) + (xcd - r) * q) + idx;

    const int wave = threadIdx.x >> 6;
    const int lane = threadIdx.x & 63;
    const int node = bid * 4 + wave;
    if (node >= n) return;

    const int2 rg = rng[node];
    const int beg = rg.x;
    const int end = rg.y;
    const uint* __restrict__ h32 = (const uint*)hb;   // bf16x2 words

    float ax = 0.f, ay = 0.f;
    int p = beg;
    for (; p + 16 <= end; p += 16) {     // deep MLP: 16 h-loads in flight
        uint m[16];
        #pragma unroll
        for (int j = 0; j < 16; ++j) m[j] = meta[p + j];
        uint h[16];
        #pragma unroll
        for (int j = 0; j < 16; ++j)
            h[j] = h32[(size_t)(m[j] & 0x1FFFFu) * 64 + lane];
        #pragma unroll
        for (int j = 0; j < 16; ++j) {
            const float w = __uint_as_float((m[j] >> 17) << 16);
            ax += __uint_as_float(h[j] << 16) * w;
            ay += __uint_as_float(h[j] & 0xffff0000u) * w;
        }
    }
    for (; p + 4 <= end; p += 4) {
        uint m[4];
        #pragma unroll
        for (int j = 0; j < 4; ++j) m[j] = meta[p + j];
        uint h[4];
        #pragma unroll
        for (int j = 0; j < 4; ++j)
            h[j] = h32[(size_t)(m[j] & 0x1FFFFu) * 64 + lane];
        #pragma unroll
        for (int j = 0; j < 4; ++j) {
            const float w = __uint_as_float((m[j] >> 17) << 16);
            ax += __uint_as_float(h[j] << 16) * w;
            ay += __uint_as_float(h[j] & 0xffff0000u) * w;
        }
    }
    for (; p < end; ++p) {
        const uint m = meta[p];
        const uint h = h32[(size_t)(m & 0x1FFFFu) * 64 + lane];
        const float w = __uint_as_float((m >> 17) << 16);
        ax += __uint_as_float(h << 16) * w;
        ay += __uint_as_float(h & 0xffff0000u) * w;
    }

    const float c = cv[node];
    float2 o; o.x = ax * c; o.y = ay * c;
    ((float2*)out)[(size_t)node * 64 + lane] = o;
}

// -------- fallback (small ws / n too large for packing) --------------------
__global__ __launch_bounds__(256) void gemm_cu_kernel(
    const float* __restrict__ feat, const float* __restrict__ Wg,
    const float* __restrict__ cu, float* __restrict__ h_src, int n)
{
    __shared__ float wlds[128 * 128];
    __shared__ float ftile[128][32];
    const int tid = threadIdx.x;
    for (int i = tid; i < (128 * 128) / 4; i += 256)
        ((float4*)wlds)[i] = ((const float4*)Wg)[i];
    const int row0 = blockIdx.x * 32;
    {
        const int r  = tid & 31;
        const int kq = tid >> 5;
        const int grow = row0 + r;
        if (grow < n) {
            #pragma unroll
            for (int c = 0; c < 4; ++c) {
                float4 v = *(const float4*)(feat + (size_t)grow * 128 + kq * 16 + c * 4);
                ftile[kq * 16 + c * 4 + 0][r] = v.x;
                ftile[kq * 16 + c * 4 + 1][r] = v.y;
                ftile[kq * 16 + c * 4 + 2][r] = v.z;
                ftile[kq * 16 + c * 4 + 3][r] = v.w;
            }
        }
    }
    __syncthreads();
    const int d0 = (tid & 31) * 4;
    const int r0 = (tid >> 5) * 4;
    float acc[4][4] = {};
    #pragma unroll 8
    for (int k = 0; k < 128; ++k) {
        const float4 a = *(const float4*)&ftile[k][r0];
        const float4 b = *(const float4*)&wlds[k * 128 + d0];
        acc[0][0] += a.x * b.x; acc[0][1] += a.x * b.y; acc[0][2] += a.x * b.z; acc[0][3] += a.x * b.w;
        acc[1][0] += a.y * b.x; acc[1][1] += a.y * b.y; acc[1][2] += a.y * b.z; acc[1][3] += a.y * b.w;
        acc[2][0] += a.z * b.x; acc[2][1] += a.z * b.y; acc[2][2] += a.z * b.z; acc[2][3] += a.z * b.w;
        acc[3][0] += a.w * b.x; acc[3][1] += a.w * b.y; acc[3][2] += a.w * b.z; acc[3][3] += a.w * b.w;
    }
    #pragma unroll
    for (int i = 0; i < 4; ++i) {
        const int rr = row0 + r0 + i;
        if (rr < n) {
            const float c = cu[rr];
            float4 o;
            o.x = acc[i][0] * c; o.y = acc[i][1] * c;
            o.z = acc[i][2] * c; o.w = acc[i][3] * c;
            *(float4*)(h_src + (size_t)rr * 128 + d0) = o;
        }
    }
}

__global__ __launch_bounds__(256) void scatter_atomic_kernel(
    const float* __restrict__ h_src, const int* __restrict__ src,
    const int* __restrict__ dst, const float* __restrict__ edge_w,
    float* __restrict__ out, int e)
{
    long long t = (long long)blockIdx.x * 256 + threadIdx.x;
    int edge = (int)(t >> 5);
    int c4   = (int)(t & 31) * 4;
    if (edge >= e) return;
    int s = src[edge], d = dst[edge];
    float w = edge_w[edge];
    const float4 h = *(const float4*)(h_src + (size_t)s * 128 + c4);
    float* o = out + (size_t)d * 128 + c4;
    atomicAdd(o + 0, h.x * w);
    atomicAdd(o + 1, h.y * w);
    atomicAdd(o + 2, h.z * w);
    atomicAdd(o + 3, h.w * w);
}

__global__ __launch_bounds__(256) void cvscale_kernel(
    float* __restrict__ out, const float* __restrict__ cv, int n)
{
    size_t i = (size_t)blockIdx.x * 256 + threadIdx.x;
    if (i < (size_t)n * 128) out[i] *= cv[i >> 7];
}

// ---------------------------------------------------------------------------

static inline size_t align_up(size_t x, size_t a) { return (x + a - 1) & ~(a - 1); }

extern "C" void kernel_launch(void* const* d_in, const int* in_sizes, int n_in,
                              void* d_out, int out_size, void* d_ws, size_t ws_size,
                              hipStream_t stream)
{
    const float* feat   = (const float*)d_in[0];
    const float* W      = (const float*)d_in[1];
    const float* cu     = (const float*)d_in[2];
    const float* cv     = (const float*)d_in[3];
    const float* edge_w = (const float*)d_in[4];
    const int*   src    = (const int*)d_in[5];
    const int*   dst    = (const int*)d_in[6];
    float* out = (float*)d_out;

    const int n = in_sizes[2];   // N
    const int e = in_sizes[5];   // E
    const int nb = (n + (1 << BSHIFT) - 1) >> BSHIFT; // coarse buckets (<=256)

    // over-allocated bucket capacity (uniform dst => cap never hit)
    const int avg = (e + nb - 1) / nb;
    const int cap = (avg + avg / 2 + 2048 + 31) & ~31;
    const size_t slots = (size_t)nb * cap;

    // workspace layout
    char* ws = (char*)d_ws;
    size_t off = 0;
    ushort* hb  = (ushort*)(ws + off); off += align_up((size_t)n * 128 * sizeof(ushort), 256);
    int2*  rng  = (int2*)(ws + off);   off += align_up((size_t)n * sizeof(int2), 256);
    int*   ccur = (int*)(ws + off);    off += align_up(256 * sizeof(int), 256);
    ushort* wbf = (ushort*)(ws + off); off += align_up(128 * 128 * sizeof(ushort), 256);
    uint*  meta = (uint*)(ws + off);   off += align_up(slots * sizeof(uint), 256);
    uint2* tmp  = (uint2*)(ws + off);  off += align_up(slots * sizeof(uint2), 256);
    const size_t need_primary = off;
    const size_t need_fallback = align_up((size_t)n * 128 * sizeof(float), 256);

    const bool pack_ok = (n <= (1 << 17)) && (nb <= 256);

    if (pack_ok && ws_size >= need_primary) {
        wconv_kernel<<<64, 256, 0, stream>>>(W, wbf, ccur);
        gemm_mfma_kernel<<<(n + 255) / 256, 256, 0, stream>>>(feat, wbf, cu, hb, n);
        coarse_fill_kernel<<<(e + CF_CHUNK - 1) / CF_CHUNK, 256, 0, stream>>>(
            src, dst, edge_w, ccur, tmp, cap, e);
        bucket_finalize_kernel<<<nb, 1024, 0, stream>>>(tmp, ccur, cap, rng, meta, n);
        gather_kernel<<<(n + 3) / 4, 256, 0, stream>>>(hb, rng, meta, cv, out, n);
    } else if (ws_size >= need_fallback) {
        float* h_src = (float*)ws;
        hipMemsetAsync(out, 0, (size_t)n * 128 * sizeof(float), stream);
        gemm_cu_kernel<<<(n + 31) / 32, 256, 0, stream>>>(feat, W, cu, h_src, n);
        const long long thr = (long long)e * 32;
        scatter_atomic_kernel<<<(int)((thr + 255) / 256), 256, 0, stream>>>(h_src, src, dst, edge_w, out, e);
        cvscale_kernel<<<(int)(((size_t)n * 128 + 255) / 256), 256, 0, stream>>>(out, cv, n);
    }
}

// Round 10
// 132.205 us; speedup vs baseline: 1.3735x; 1.0338x over previous
//
#include <hip/hip_runtime.h>

// ---------------------------------------------------------------------------
// InfluenceGraphConv: out = segment_sum((feat@W * cu)[src] * edge_w, dst) * cv
// N=100000, E=1600000, D_IN=D_OUT=128, fp32 in/out (src/dst int32).
//
// 5-dispatch pipeline:
//   0. wconv:           W -> bf16 W^T, PRE-SWIZZLED bytes (LDS-image);
//                       also zeroes the 256 coarse-bucket cursors
//   1. gemm_mfma:       hb[n][d] = bf16((feat[n].W[:,d]) * cu[n]);
//                       W staged into LDS as 8 uint4 copies/thread
//   2. coarse_fill:     LDS-staged binning into 512-node buckets at
//                       implicit base b*cap (over-allocated, no scan)
//   3. bucket_finalize: per-bucket LDS count + ALIGNED scan (each node's
//                       meta segment starts at a multiple of 4) -> rng;
//                       scatter -> meta (4B: src(17b)|w_bf15<<17); 1024 thr
//   4. gather:          one wave per node, bf16 rows, 8-deep unroll,
//                       meta read as uint4 (segments 4-aligned)
// All CSR-build atomics in LDS; no float atomics; output written once.
// ---------------------------------------------------------------------------

typedef __attribute__((ext_vector_type(8))) short short8;
typedef __attribute__((ext_vector_type(4))) float f32x4;

#define BSHIFT 9                    // 512 nodes per coarse bucket
#define CF_CHUNK 4096               // edges per coarse_fill block

static __device__ __forceinline__ ushort f2bf(float f) {
    uint b = __float_as_uint(f);
    uint r = b + 0x7fff + ((b >> 16) & 1);   // RNE
    return (ushort)(r >> 16);
}

// ---- 0. W pre-convert: bf16 W^T with the gemm LDS swizzle baked in --------
__global__ __launch_bounds__(256) void wconv_kernel(
    const float* __restrict__ Wg, ushort* __restrict__ wbf,
    int* __restrict__ ccur)
{
    const int tid = threadIdx.x;
    if (blockIdx.x == 0) ccur[tid] = 0;      // stream-ordered before fill
    char* const wp = (char*)wbf;
    for (int i = blockIdx.x * 256 + tid; i < 128 * 128; i += gridDim.x * 256) {
        const int k = i >> 7, d = i & 127;   // W[k][d]
        const int byte_addr = (d * 256 + k * 2) ^ ((d & 7) << 4);
        *(ushort*)(wp + byte_addr) = f2bf(Wg[i]);
    }
}

// ---- 1. bf16 MFMA GEMM + cu scale, bf16 output ----------------------------
__global__ __launch_bounds__(256) void gemm_mfma_kernel(
    const float* __restrict__ feat, const ushort* __restrict__ wbf,
    const float* __restrict__ cu, ushort* __restrict__ hb, int n)
{
    __shared__ ushort wt[128 * 128];      // 32 KB, byte-image of wbf
    char* const wp = (char*)wt;
    const int tid  = threadIdx.x;
    const int lane = tid & 63;
    const int wid  = tid >> 6;

    // stage pre-swizzled W: 2048 uint4 = 8 per thread
    {
        const uint4* wv = (const uint4*)wbf;
        #pragma unroll
        for (int j = 0; j < 8; ++j)
            ((uint4*)wt)[tid + j * 256] = wv[tid + j * 256];
    }
    __syncthreads();

    const int wave_row0 = blockIdx.x * 256 + wid * 64;

    for (int rt = 0; rt < 4; ++rt) {
        const int r0 = wave_row0 + rt * 16;
        const int arow = min(r0 + (lane & 15), n - 1);
        const float* ap = feat + (size_t)arow * 128 + ((lane >> 4) * 8);

        short8 afr[4];
        #pragma unroll
        for (int kk = 0; kk < 4; ++kk) {
            const float4 f0 = *(const float4*)(ap + kk * 32);
            const float4 f1 = *(const float4*)(ap + kk * 32 + 4);
            short8 a;
            a[0] = (short)f2bf(f0.x); a[1] = (short)f2bf(f0.y);
            a[2] = (short)f2bf(f0.z); a[3] = (short)f2bf(f0.w);
            a[4] = (short)f2bf(f1.x); a[5] = (short)f2bf(f1.y);
            a[6] = (short)f2bf(f1.z); a[7] = (short)f2bf(f1.w);
            afr[kk] = a;
        }

        f32x4 acc[8];
        #pragma unroll
        for (int nf = 0; nf < 8; ++nf) acc[nf] = (f32x4)(0.f);

        #pragma unroll
        for (int kk = 0; kk < 4; ++kk) {
            const int kbyte = kk * 64 + ((lane >> 4) << 4);
            #pragma unroll
            for (int nf = 0; nf < 8; ++nf) {
                const int col = nf * 16 + (lane & 15);
                const short8 bfr = *(const short8*)(
                    wp + ((col * 256 + kbyte) ^ ((col & 7) << 4)));
                acc[nf] = __builtin_amdgcn_mfma_f32_16x16x32_bf16(
                    afr[kk], bfr, acc[nf], 0, 0, 0);
            }
        }

        const int rbase = r0 + (lane >> 4) * 4;
        float cuv[4];
        #pragma unroll
        for (int i = 0; i < 4; ++i) cuv[i] = cu[min(rbase + i, n - 1)];
        #pragma unroll
        for (int nf = 0; nf < 8; ++nf) {
            const int col = nf * 16 + (lane & 15);
            #pragma unroll
            for (int i = 0; i < 4; ++i) {
                const int row = rbase + i;
                if (row < n)
                    hb[(size_t)row * 128 + col] = f2bf(acc[nf][i] * cuv[i]);
            }
        }
    }
}

// ---- 2. coarse fill: LDS-staged binning into 512-node buckets -------------
// tmp entry: x = src | (dstoff<<17)  (requires n <= 131072), y = bits(edge_w)
// bucket b's region = tmp[b*cap .. b*cap+ccur[b])
__global__ __launch_bounds__(256) void coarse_fill_kernel(
    const int* __restrict__ src, const int* __restrict__ dst,
    const float* __restrict__ edge_w, int* __restrict__ ccur,
    uint2* __restrict__ tmp, int cap, int e)
{
    __shared__ uint   le0[CF_CHUNK];     // 16 KB
    __shared__ uint   lw[CF_CHUNK];      // 16 KB
    __shared__ ushort lb[CF_CHUNK];      //  8 KB (bucket id; 0xFFFF = invalid)
    __shared__ int    hist[256];
    __shared__ int    hbase[256];
    __shared__ int    lcur[256];
    const int tid  = threadIdx.x;
    const int base = blockIdx.x * CF_CHUNK;

    hist[tid] = 0; lcur[tid] = 0;
    __syncthreads();

    #pragma unroll
    for (int j = 0; j < CF_CHUNK / 256; ++j) {
        const int i  = base + j * 256 + tid;
        const int li = j * 256 + tid;
        if (i < e) {
            const int d = dst[i];
            const int b = d >> BSHIFT;
            le0[li] = (uint)src[i] | ((uint)(d & ((1 << BSHIFT) - 1)) << 17);
            lw[li]  = __float_as_uint(edge_w[i]);
            lb[li]  = (ushort)b;
            atomicAdd(&hist[b], 1);
        } else {
            lb[li] = 0xFFFF;
        }
    }
    __syncthreads();

    if (hist[tid] > 0)
        hbase[tid] = tid * cap + atomicAdd(&ccur[tid], hist[tid]);
    __syncthreads();

    #pragma unroll
    for (int j = 0; j < CF_CHUNK / 256; ++j) {
        const int li = j * 256 + tid;
        const ushort b = lb[li];
        if (b != 0xFFFF) {
            const int pos = hbase[b] + atomicAdd(&lcur[b], 1);
            if (pos < (b + 1) * cap) {            // overflow guard
                uint2 v; v.x = le0[li]; v.y = lw[li];
                tmp[pos] = v;
            }
        }
    }
}

// ---- 3. per-bucket finalize: LDS count + ALIGNED scan -> rng; scatter -----
// meta entry (4B): src(17b) | w_bf15(15b)<<17; each node's segment starts at
// a 4-entry boundary (padding never read by gather)
__global__ __launch_bounds__(1024) void bucket_finalize_kernel(
    const uint2* __restrict__ tmp, const int* __restrict__ ccur, int cap,
    int2* __restrict__ rng, uint* __restrict__ meta, int n)
{
    __shared__ int lcnt[512];
    __shared__ int lcur[512];
    __shared__ int wsum[16];
    const int b = blockIdx.x;
    const int tid  = threadIdx.x;
    const int lane = tid & 63;
    const int wid  = tid >> 6;
    const int base = b * cap;
    const int cnt  = min(ccur[b], cap);
    const int ce   = base + cnt;
    const int node0 = b << BSHIFT;
    const int nn = min(1 << BSHIFT, n - node0);

    if (tid < 512) lcnt[tid] = 0;
    __syncthreads();

    for (int i = base + tid; i < ce; i += 1024)
        atomicAdd(&lcnt[(tmp[i].x >> 17) & ((1 << BSHIFT) - 1)], 1);
    __syncthreads();

    // block exclusive scan of ceil4(lcnt) (threads >=512 contribute 0)
    const int v = (tid < 512) ? lcnt[tid] : 0;
    const int w = (v + 3) & ~3;                 // 4-aligned segment size
    int incl = w;
    #pragma unroll
    for (int off = 1; off < 64; off <<= 1) {
        int t = __shfl_up(incl, off);
        if (lane >= off) incl += t;
    }
    if (lane == 63) wsum[wid] = incl;
    __syncthreads();
    int wpre = 0;
    for (int k = 0; k < wid; ++k) wpre += wsum[k];
    const int excl = wpre + incl - w;           // 4-aligned start
    if (tid < 512) lcur[tid] = excl;

    if (tid < nn) {
        int2 rr; rr.x = base + excl; rr.y = base + excl + v;
        rng[node0 + tid] = rr;
    }
    __syncthreads();

    // scatter into node-sorted meta (bucket region is L2-local)
    for (int i = base + tid; i < ce; i += 1024) {
        const uint2 t2 = tmp[i];
        const int local = (t2.x >> 17) & ((1 << BSHIFT) - 1);
        const int pos = atomicAdd(&lcur[local], 1);
        if (pos < cap) {                        // guard (pathological skew)
            const uint wb = t2.y;               // fp32 bits, w >= 0
            const uint w15 = ((wb + 0x7fffu + ((wb >> 16) & 1u)) >> 16) & 0x7FFFu;
            meta[base + pos] = (t2.x & 0x1FFFFu) | (w15 << 17);
        }
    }
}

// ---- 4. gather: one wave per node, bf16 rows, 8-deep, uint4 meta ----------
__global__ __launch_bounds__(256) void gather_kernel(
    const ushort* __restrict__ hb, const int2* __restrict__ rng,
    const uint* __restrict__ meta, const float* __restrict__ cv,
    float* __restrict__ out, int n)
{
    // bijective XCD-chunked swizzle (m204): contiguous node ranges per XCD
    const int nwg = gridDim.x;
    const int q = nwg >> 3, r = nwg & 7;
    const int xcd = blockIdx.x & 7, idx = blockIdx.x >> 3;
    const int bid = (xcd < r ? xcd * (q + 1) : r * (q + 1) + (xcd - r) * q) + idx;

    const int wave = threadIdx.x >> 6;
    const int lane = threadIdx.x & 63;
    const int node = bid * 4 + wave;
    if (node >= n) return;

    const int2 rg = rng[node];
    const int beg = rg.x;                 // 4-aligned by construction
    const int end = rg.y;
    const uint* __restrict__ h32 = (const uint*)hb;   // bf16x2 words

    float ax = 0.f, ay = 0.f;
    int p = beg;
    for (; p + 8 <= end; p += 8) {
        const uint4 ma = *(const uint4*)(meta + p);
        const uint4 mb = *(const uint4*)(meta + p + 4);
        const uint m[8] = {ma.x, ma.y, ma.z, ma.w, mb.x, mb.y, mb.z, mb.w};
        uint h[8];
        #pragma unroll
        for (int j = 0; j < 8; ++j)
            h[j] = h32[(size_t)(m[j] & 0x1FFFFu) * 64 + lane];
        #pragma unroll
        for (int j = 0; j < 8; ++j) {
            const float w = __uint_as_float((m[j] >> 17) << 16);
            ax += __uint_as_float(h[j] << 16) * w;
            ay += __uint_as_float(h[j] & 0xffff0000u) * w;
        }
    }
    for (; p + 4 <= end; p += 4) {
        const uint4 ma = *(const uint4*)(meta + p);
        const uint m[4] = {ma.x, ma.y, ma.z, ma.w};
        uint h[4];
        #pragma unroll
        for (int j = 0; j < 4; ++j)
            h[j] = h32[(size_t)(m[j] & 0x1FFFFu) * 64 + lane];
        #pragma unroll
        for (int j = 0; j < 4; ++j) {
            const float w = __uint_as_float((m[j] >> 17) << 16);
            ax += __uint_as_float(h[j] << 16) * w;
            ay += __uint_as_float(h[j] & 0xffff0000u) * w;
        }
    }
    for (; p < end; ++p) {
        const uint m = meta[p];
        const uint h = h32[(size_t)(m & 0x1FFFFu) * 64 + lane];
        const float w = __uint_as_float((m >> 17) << 16);
        ax += __uint_as_float(h << 16) * w;
        ay += __uint_as_float(h & 0xffff0000u) * w;
    }

    const float c = cv[node];
    float2 o; o.x = ax * c; o.y = ay * c;
    ((float2*)out)[(size_t)node * 64 + lane] = o;
}

// -------- fallback (small ws / n too large for packing) --------------------
__global__ __launch_bounds__(256) void gemm_cu_kernel(
    const float* __restrict__ feat, const float* __restrict__ Wg,
    const float* __restrict__ cu, float* __restrict__ h_src, int n)
{
    __shared__ float wlds[128 * 128];
    __shared__ float ftile[128][32];
    const int tid = threadIdx.x;
    for (int i = tid; i < (128 * 128) / 4; i += 256)
        ((float4*)wlds)[i] = ((const float4*)Wg)[i];
    const int row0 = blockIdx.x * 32;
    {
        const int r  = tid & 31;
        const int kq = tid >> 5;
        const int grow = row0 + r;
        if (grow < n) {
            #pragma unroll
            for (int c = 0; c < 4; ++c) {
                float4 v = *(const float4*)(feat + (size_t)grow * 128 + kq * 16 + c * 4);
                ftile[kq * 16 + c * 4 + 0][r] = v.x;
                ftile[kq * 16 + c * 4 + 1][r] = v.y;
                ftile[kq * 16 + c * 4 + 2][r] = v.z;
                ftile[kq * 16 + c * 4 + 3][r] = v.w;
            }
        }
    }
    __syncthreads();
    const int d0 = (tid & 31) * 4;
    const int r0 = (tid >> 5) * 4;
    float acc[4][4] = {};
    #pragma unroll 8
    for (int k = 0; k < 128; ++k) {
        const float4 a = *(const float4*)&ftile[k][r0];
        const float4 b = *(const float4*)&wlds[k * 128 + d0];
        acc[0][0] += a.x * b.x; acc[0][1] += a.x * b.y; acc[0][2] += a.x * b.z; acc[0][3] += a.x * b.w;
        acc[1][0] += a.y * b.x; acc[1][1] += a.y * b.y; acc[1][2] += a.y * b.z; acc[1][3] += a.y * b.w;
        acc[2][0] += a.z * b.x; acc[2][1] += a.z * b.y; acc[2][2] += a.z * b.z; acc[2][3] += a.z * b.w;
        acc[3][0] += a.w * b.x; acc[3][1] += a.w * b.y; acc[3][2] += a.w * b.z; acc[3][3] += a.w * b.w;
    }
    #pragma unroll
    for (int i = 0; i < 4; ++i) {
        const int rr = row0 + r0 + i;
        if (rr < n) {
            const float c = cu[rr];
            float4 o;
            o.x = acc[i][0] * c; o.y = acc[i][1] * c;
            o.z = acc[i][2] * c; o.w = acc[i][3] * c;
            *(float4*)(h_src + (size_t)rr * 128 + d0) = o;
        }
    }
}

__global__ __launch_bounds__(256) void scatter_atomic_kernel(
    const float* __restrict__ h_src, const int* __restrict__ src,
    const int* __restrict__ dst, const float* __restrict__ edge_w,
    float* __restrict__ out, int e)
{
    long long t = (long long)blockIdx.x * 256 + threadIdx.x;
    int edge = (int)(t >> 5);
    int c4   = (int)(t & 31) * 4;
    if (edge >= e) return;
    int s = src[edge], d = dst[edge];
    float w = edge_w[edge];
    const float4 h = *(const float4*)(h_src + (size_t)s * 128 + c4);
    float* o = out + (size_t)d * 128 + c4;
    atomicAdd(o + 0, h.x * w);
    atomicAdd(o + 1, h.y * w);
    atomicAdd(o + 2, h.z * w);
    atomicAdd(o + 3, h.w * w);
}

__global__ __launch_bounds__(256) void cvscale_kernel(
    float* __restrict__ out, const float* __restrict__ cv, int n)
{
    size_t i = (size_t)blockIdx.x * 256 + threadIdx.x;
    if (i < (size_t)n * 128) out[i] *= cv[i >> 7];
}

// ---------------------------------------------------------------------------

static inline size_t align_up(size_t x, size_t a) { return (x + a - 1) & ~(a - 1); }

extern "C" void kernel_launch(void* const* d_in, const int* in_sizes, int n_in,
                              void* d_out, int out_size, void* d_ws, size_t ws_size,
                              hipStream_t stream)
{
    const float* feat   = (const float*)d_in[0];
    const float* W      = (const float*)d_in[1];
    const float* cu     = (const float*)d_in[2];
    const float* cv     = (const float*)d_in[3];
    const float* edge_w = (const float*)d_in[4];
    const int*   src    = (const int*)d_in[5];
    const int*   dst    = (const int*)d_in[6];
    float* out = (float*)d_out;

    const int n = in_sizes[2];   // N
    const int e = in_sizes[5];   // E
    const int nb = (n + (1 << BSHIFT) - 1) >> BSHIFT; // coarse buckets (<=256)

    // over-allocated bucket capacity (uniform dst => cap never hit;
    // slack also covers the +<=2048 per-bucket 4-alignment padding)
    const int avg = (e + nb - 1) / nb;
    const int cap = (avg + avg / 2 + 4096 + 31) & ~31;
    const size_t slots = (size_t)nb * cap;

    // workspace layout
    char* ws = (char*)d_ws;
    size_t off = 0;
    ushort* hb  = (ushort*)(ws + off); off += align_up((size_t)n * 128 * sizeof(ushort), 256);
    int2*  rng  = (int2*)(ws + off);   off += align_up((size_t)n * sizeof(int2), 256);
    int*   ccur = (int*)(ws + off);    off += align_up(256 * sizeof(int), 256);
    ushort* wbf = (ushort*)(ws + off); off += align_up(128 * 128 * sizeof(ushort), 256);
    uint*  meta = (uint*)(ws + off);   off += align_up(slots * sizeof(uint), 256);
    uint2* tmp  = (uint2*)(ws + off);  off += align_up(slots * sizeof(uint2), 256);
    const size_t need_primary = off;
    const size_t need_fallback = align_up((size_t)n * 128 * sizeof(float), 256);

    const bool pack_ok = (n <= (1 << 17)) && (nb <= 256);

    if (pack_ok && ws_size >= need_primary) {
        wconv_kernel<<<64, 256, 0, stream>>>(W, wbf, ccur);
        gemm_mfma_kernel<<<(n + 255) / 256, 256, 0, stream>>>(feat, wbf, cu, hb, n);
        coarse_fill_kernel<<<(e + CF_CHUNK - 1) / CF_CHUNK, 256, 0, stream>>>(
            src, dst, edge_w, ccur, tmp, cap, e);
        bucket_finalize_kernel<<<nb, 1024, 0, stream>>>(tmp, ccur, cap, rng, meta, n);
        gather_kernel<<<(n + 3) / 4, 256, 0, stream>>>(hb, rng, meta, cv, out, n);
    } else if (ws_size >= need_fallback) {
        float* h_src = (float*)ws;
        hipMemsetAsync(out, 0, (size_t)n * 128 * sizeof(float), stream);
        gemm_cu_kernel<<<(n + 31) / 32, 256, 0, stream>>>(feat, W, cu, h_src, n);
        const long long thr = (long long)e * 32;
        scatter_atomic_kernel<<<(int)((thr + 255) / 256), 256, 0, stream>>>(h_src, src, dst, edge_w, out, e);
        cvscale_kernel<<<(int)(((size_t)n * 128 + 255) / 256), 256, 0, stream>>>(out, cv, n);
    }
}